// Round 19
// baseline (46.988 us; speedup 1.0000x reference)
//
#include <hip/hip_runtime.h>
#include <hip/hip_bf16.h>

typedef _Float16 f16x8 __attribute__((ext_vector_type(8)));
typedef float    f32x4 __attribute__((ext_vector_type(4)));

constexpr int BB  = 4096;
constexpr int AA  = 64;
constexpr int ED  = 10;
constexpr int P1N = 32, P2N = 128, P3N = 256;
constexpr int PT  = 416;          // = 13 * 32
constexpr int NKS = 13;           // K-steps of 32
constexpr int BCH = 64;           // b rows per block
constexpr int NCH = 8;            // a-channels per block (f16x8 per slot)

constexpr int    ROWSLOTS  = 65;                      // 64 + 1 pad slot
constexpr size_t XLS_BYTES = (size_t)BCH * ROWSLOTS * 16;   // 66560
constexpr size_t LDS_BYTES = XLS_BYTES + PT * 4;            // 68224

// ---------------------------------------------------------------------------
// Merged setup (one launch):
//  blocks 0..831: cwb[aq][ks][lane][ch][8] = f16(coeff[p]*w[e,k[p],q[p],a]),
//    p = ks*32 + (lane>>4)*8 + j, e = lane&15 (0 for e>=10), a = aq*8+ch.
//    -> one lane's 8 channel-frags per kstep are CONTIGUOUS 128 B (2 lines).
//  block 832: idxs[p] = (sa*16) | (sb*16)<<11 | sc<<22  (sa,sb pre-scaled to
//    byte offsets of 16-B slots; sc raw, scaled at use).
// ---------------------------------------------------------------------------
__global__ void build_tables_kernel(
    const float* __restrict__ w1, const float* __restrict__ w2, const float* __restrict__ w3,
    const float* __restrict__ c1, const float* __restrict__ c2, const float* __restrict__ c3,
    const int* __restrict__ k1, const int* __restrict__ q1,
    const int* __restrict__ k2, const int* __restrict__ q2,
    const int* __restrict__ k3, const int* __restrict__ q3,
    const int* __restrict__ i1, const int* __restrict__ l1,
    const int* __restrict__ i2, const int* __restrict__ j2,
    const int* __restrict__ l2, const int* __restrict__ m2,
    const int* __restrict__ i3, const int* __restrict__ j3,
    const int* __restrict__ f3, const int* __restrict__ l3,
    const int* __restrict__ m3, const int* __restrict__ g3,
    _Float16* __restrict__ cwb, unsigned* __restrict__ idxs) {
  if (blockIdx.x == AA * NKS) {
    for (int p = threadIdx.x; p < PT; p += 64) {
      unsigned sa, sb = 0, sc = 0;
      if (p < P1N) {
        sa = i1[p] * 4 + l1[p];
      } else if (p < P1N + P2N) {
        int pp = p - P1N;
        sa = i2[pp] * 4 + l2[pp];
        sb = j2[pp] * 4 + m2[pp];
      } else {
        int pp = p - P1N - P2N;
        sa = i3[pp] * 4 + l3[pp];
        sb = j3[pp] * 4 + m3[pp];
        sc = f3[pp] * 4 + g3[pp];
      }
      idxs[p] = (sa * 16) | ((sb * 16) << 11) | (sc << 22);
    }
    return;
  }
  const int a  = blockIdx.x & 63;
  const int ks = blockIdx.x >> 6;   // 0..12
  const int l  = threadIdx.x;       // 0..63
  const int grp = l >> 4, e = l & 15;
  const int aq = a >> 3, ch = a & 7;
  _Float16* dst = cwb + ((((size_t)aq * NKS + ks) * 64 + l) * 8 + ch) * 8;
  #pragma unroll
  for (int j = 0; j < 8; ++j) {
    const int p = ks * 32 + grp * 8 + j;
    float v = 0.f;
    if (e < ED) {
      const float* w; float coeff; int k, q, K, Q;
      if (p < P1N)            { w = w1; coeff = c1[p]; k = k1[p]; q = q1[p]; K = 4;  Q = 2; }
      else if (p < P1N + P2N) { int pp = p - P1N;       w = w2; coeff = c2[pp]; k = k2[pp]; q = q2[pp]; K = 16; Q = 4; }
      else                    { int pp = p - P1N - P2N; w = w3; coeff = c3[pp]; k = k3[pp]; q = q3[pp]; K = 32; Q = 6; }
      v = coeff * w[(((size_t)e * K + k) * Q + q) * AA + a];
    }
    dst[j] = (_Float16)v;
  }
}

// ---------------------------------------------------------------------------
// One K-step, pure SSA. One ds_read_b128 gather serves 8 a-channels.
// idx from LDS; B-frags 8 contiguous f16x8 (128 B).
// ---------------------------------------------------------------------------
template <int NF, int KS>
__device__ __forceinline__ void kstep(
    const char* rowb, const uint4* ip,
    const f16x8* __restrict__ cwq, f32x4 (&ac)[NCH]) {
  const uint4 iA = ip[KS * 8 + 0];
  const uint4 iB = ip[KS * 8 + 1];
  const f16x8* c = cwq + KS * 512;   // 512 f16x8 per kstep (64 lanes x 8 ch)
  f16x8 bfr[NCH];
  #pragma unroll
  for (int ch = 0; ch < NCH; ++ch) bfr[ch] = c[ch];
  const unsigned pks[8] = {iA.x, iA.y, iA.z, iA.w, iB.x, iB.y, iB.z, iB.w};
  f16x8 af[NCH];
  #pragma unroll
  for (int jh = 0; jh < 2; ++jh) {
    f16x8 g0[4], g1[4], g2[4];
    #pragma unroll
    for (int j = 0; j < 4; ++j) {
      const unsigned pk = pks[jh * 4 + j];
      g0[j] = *(const f16x8*)(rowb + (pk & 2047u));
      if (NF >= 2) g1[j] = *(const f16x8*)(rowb + ((pk >> 11) & 2047u));
      if (NF >= 3) g2[j] = *(const f16x8*)(rowb + ((pk >> 22) << 4));
    }
    #pragma unroll
    for (int j = 0; j < 4; ++j) {
      f16x8 v = g0[j];
      if (NF >= 2) v = v * g1[j];
      if (NF >= 3) v = v * g2[j];
      const int jj = jh * 4 + j;
      #pragma unroll
      for (int ch = 0; ch < NCH; ++ch) af[ch][jj] = v[ch];
    }
  }
  #pragma unroll
  for (int ch = 0; ch < NCH; ++ch)
    ac[ch] = __builtin_amdgcn_mfma_f32_16x16x32_f16(af[ch], bfr[ch], ac[ch], 0, 0, 0);
}

// ---------------------------------------------------------------------------
// Main: block = a-OCTET x 64 b's; 4 waves = 4 private M-tiles, no
// __syncthreads. Dynamic LDS 68.2 KB -> 2 blocks/CU (136 <= 160 KB).
// (256,2): 256-VGPR budget -> no spill by construction. Grid 512 = 2/CU.
// Total DS instructions per chip HALVED vs NCH=4 (one b128 serves 8 ch).
// ---------------------------------------------------------------------------
__global__ __launch_bounds__(256, 2)
void contract_kernel(const float* __restrict__ x, const float* __restrict__ y,
                     const unsigned* __restrict__ idxs,
                     const f16x8* __restrict__ cwb,
                     float* __restrict__ out) {
  extern __shared__ char lds[];
  f16x8 (*xls)[ROWSLOTS] = (f16x8(*)[ROWSLOTS])lds;   // [64][65] f16x8
  uint4* ils = (uint4*)(lds + XLS_BYTES);             // idx table, 1.66 KB

  const int t  = threadIdx.x;
  const int aq = blockIdx.x & 7;
  const int a0 = aq * NCH;
  const int b0 = (blockIdx.x >> 3) * BCH;
  const int wv = t >> 6, l = t & 63, grp = l >> 4, er = l & 15;
  const int r0 = wv * 16;          // this wave's private row base

  // Stage idx table: EACH wave writes all 104 uint4 (identical values ->
  // racing writes benign; in-wave lgkmcnt orders write->read).
  {
    const uint4* gip = (const uint4*)idxs;
    for (int u = l; u < PT / 4; u += 64) ils[u] = gip[u];
  }

  // Per-wave x staging: iteration i covers rows r0+i*4..+3; lane l handles
  // row r0+i*4+(l>>4), slots 4*(l&15)..+3. Eight float4 loads (one per
  // channel), cvt+transpose to 4 f16x8 slots, 64 B contiguous LDS write.
  #pragma unroll
  for (int i = 0; i < 4; ++i) {
    const int row = r0 + i * 4 + (l >> 4);
    const int s   = (l & 15) * 4;
    const float* xb = x + (size_t)(b0 + row) * 4096 + a0 * 64 + s;
    float4 L[NCH];
    #pragma unroll
    for (int ch = 0; ch < NCH; ++ch) L[ch] = *(const float4*)(xb + 64 * ch);
    #pragma unroll
    for (int k = 0; k < 4; ++k) {
      f16x8 v;
      #pragma unroll
      for (int ch = 0; ch < NCH; ++ch) v[ch] = (_Float16)((&L[ch].x)[k]);
      xls[row][s + k] = v;
    }
  }
  // NO __syncthreads: wave reads only its own writes (in-wave lgkmcnt).
  // Slot 64 is pure bank-padding (NF-specialized ksteps never read it).

  const char* rowb = (const char*)&xls[r0 + er][0];
  const f16x8* __restrict__ cwq = cwb + (size_t)aq * NKS * 512 + (size_t)l * 8;
  const uint4* ip = &ils[grp * 2];

  f32x4 ac[NCH];
  #pragma unroll
  for (int ch = 0; ch < NCH; ++ch) ac[ch] = f32x4{0.f, 0.f, 0.f, 0.f};

  #define STEP(NF, KS) kstep<NF, KS>(rowb, ip, cwq, ac)
  STEP(1, 0);                                       // path 1
  STEP(2, 1); STEP(2, 2); STEP(2, 3); STEP(2, 4);   // path 2
  STEP(3, 5); STEP(3, 6); STEP(3, 7); STEP(3, 8);   // path 3
  STEP(3, 9); STEP(3, 10); STEP(3, 11); STEP(3, 12);
  #undef STEP

  // Epilogue: D[row = grp*4+v][col = er], y-weight (direct global read,
  // zero for er>=10), 16-lane shfl reduce over e.
  const int rbase = b0 + r0 + grp * 4;
  float ye[4];
  #pragma unroll
  for (int r = 0; r < 4; ++r)
    ye[r] = (er < ED) ? y[(size_t)(rbase + r) * ED + er] : 0.f;

  #pragma unroll
  for (int c = 0; c < NCH; ++c) {
    float s0 = ac[c][0] * ye[0];
    float s1 = ac[c][1] * ye[1];
    float s2 = ac[c][2] * ye[2];
    float s3 = ac[c][3] * ye[3];
    #pragma unroll
    for (int m = 1; m < 16; m <<= 1) {
      s0 += __shfl_xor(s0, m);
      s1 += __shfl_xor(s1, m);
      s2 += __shfl_xor(s2, m);
      s3 += __shfl_xor(s3, m);
    }
    if (er < 4) {
      const float sv = er == 0 ? s0 : er == 1 ? s1 : er == 2 ? s2 : s3;
      out[(size_t)(rbase + er) * AA + (a0 + c)] = sv;
    }
  }
}

// ---------------------------------------------------------------------------
extern "C" void kernel_launch(void* const* d_in, const int* in_sizes, int n_in,
                              void* d_out, int out_size, void* d_ws, size_t ws_size,
                              hipStream_t stream) {
  const float* x  = (const float*)d_in[0];
  const float* y  = (const float*)d_in[1];
  const float* w1 = (const float*)d_in[2];
  const float* w2 = (const float*)d_in[3];
  const float* w3 = (const float*)d_in[4];
  const float* c1 = (const float*)d_in[5];
  const float* c2 = (const float*)d_in[6];
  const float* c3 = (const float*)d_in[7];
  const int* i1 = (const int*)d_in[8];
  const int* l1 = (const int*)d_in[9];
  const int* k1 = (const int*)d_in[10];
  const int* q1 = (const int*)d_in[11];
  const int* i2 = (const int*)d_in[12];
  const int* j2 = (const int*)d_in[13];
  const int* l2 = (const int*)d_in[14];
  const int* m2 = (const int*)d_in[15];
  const int* k2 = (const int*)d_in[16];
  const int* q2 = (const int*)d_in[17];
  const int* i3 = (const int*)d_in[18];
  const int* j3 = (const int*)d_in[19];
  const int* f3 = (const int*)d_in[20];
  const int* l3 = (const int*)d_in[21];
  const int* m3 = (const int*)d_in[22];
  const int* g3 = (const int*)d_in[23];
  const int* k3 = (const int*)d_in[24];
  const int* q3 = (const int*)d_in[25];

  unsigned*  idxs = (unsigned*)d_ws;                    // 416*4 B
  _Float16*  cwb  = (_Float16*)((char*)d_ws + 4096);    // 832 KB

  build_tables_kernel<<<AA * NKS + 1, 64, 0, stream>>>(
      w1, w2, w3, c1, c2, c3, k1, q1, k2, q2, k3, q3,
      i1, l1, i2, j2, l2, m2, i3, j3, f3, l3, m3, g3, cwb, idxs);

  // Opt in to >64 KB dynamic LDS (host-side attribute, graph-capture-safe,
  // idempotent -> called unconditionally every launch).
  hipFuncSetAttribute((const void*)contract_kernel,
                      hipFuncAttributeMaxDynamicSharedMemorySize,
                      (int)LDS_BYTES);
  contract_kernel<<<(AA / NCH) * (BB / BCH), 256, LDS_BYTES, stream>>>(
      x, y, idxs, (const f16x8*)cwb, (float*)d_out);
}